// Round 6
// baseline (254.513 us; speedup 1.0000x reference)
//
#include <hip/hip_runtime.h>

// DigitCaps dynamic routing, B=256 R=192 C=96 O=16 I=20. fp32 in/out.
// u_hat never materialized. 6 dispatches:
//   prep: W->WtT bf16 k-major; X->Xk + xT; zero bij + tile counters
//   gemm1_redsq (x3): 64x128 tile, split-K=10; softmax(bij) per block folded
//     into B-staging; partials P^T[z][n][b] bf16; LAST z-block per tile
//     (atomic counter + device fences) reduces+squashes -> vT / out
//   gemm2_agree (x2): Z-tile in regs; agreement contracted in epilogue,
//     atomicAdd into bij. K=256 split 2 ways.

#define R_ 192
#define C_ 96
#define O_ 16
#define I_ 20
#define B_ 256
#define K1 3840   // R*I
#define N_ 1536   // C*O
#define ZSPLIT 10
#define KCH 384       // K1/ZSPLIT, 12 BK-iters
#define STILE 393216  // N_*B_ elements per z-slice
#define PITER (ZSPLIT * STILE)

typedef unsigned short u16;
typedef __attribute__((ext_vector_type(8))) short short8;
typedef __attribute__((ext_vector_type(4))) float floatx4;

__device__ inline float bf2f(u16 h) {
  union { unsigned int u; float f; } x; x.u = ((unsigned int)h) << 16; return x.f;
}
__device__ inline u16 f2bf(float f) {
  union { float f; unsigned int u; } x; x.f = f;
  unsigned int r = x.u + 0x7FFFu + ((x.u >> 16) & 1u);
  return (u16)(r >> 16);
}
__device__ inline unsigned int pack2(float a, float b) {
  return (unsigned int)f2bf(a) | ((unsigned int)f2bf(b) << 16);
}

// ---- fused prep: WtT gather (23040 blocks); X cast+transpose (240); zeros (73)
__global__ void k_prep(const float* __restrict__ W, const float* __restrict__ X,
                       u16* __restrict__ WtT, u16* __restrict__ Xk,
                       u16* __restrict__ xT, float* __restrict__ zeroRegion) {
  int bid = blockIdx.x;
  if (bid < 23040) {
    int t = bid * 256 + threadIdx.x;           // over N_*K1 = 5,898,240
    int n = t / K1, k = t - n * K1;
    int c = n >> 4, o = n & 15;
    int r = k / I_, i = k - r * I_;
    WtT[t] = f2bf(W[(((r * C_ + c) * O_ + o) * I_) + i]);
  } else if (bid < 23280) {
    __shared__ u16 tile[64][72];
    int idx = bid - 23040;
    int kb = (idx % 60) << 6, bb = (idx / 60) << 6;
    int brow = threadIdx.x >> 4;          // 0..15
    int kq = (threadIdx.x & 15) << 2;     // 0..60 step 4
    #pragma unroll
    for (int p = 0; p < 4; ++p) {
      int bl = p * 16 + brow;
      float4 v = *(const float4*)(X + (size_t)(bb + bl) * K1 + kb + kq);
      ushort4 h;
      h.x = f2bf(v.x); h.y = f2bf(v.y); h.z = f2bf(v.z); h.w = f2bf(v.w);
      *(ushort4*)(Xk + (size_t)(bb + bl) * K1 + kb + kq) = h;
      tile[kq + 0][bl] = h.x;
      tile[kq + 1][bl] = h.y;
      tile[kq + 2][bl] = h.z;
      tile[kq + 3][bl] = h.w;
    }
    __syncthreads();
    int kr = threadIdx.x >> 3;            // 0..31
    int bq = (threadIdx.x & 7) << 3;      // 0..56 step 8
    #pragma unroll
    for (int q = 0; q < 2; ++q) {
      int kl = q * 32 + kr;
      *(uint4*)(xT + (size_t)(kb + kl) * B_ + bb + bq) = *(const uint4*)&tile[kl][bq];
    }
  } else {
    int t = (bid - 23280) * 256 + threadIdx.x;  // bij 18432 + counters 144
    if (t < 18576) zeroRegion[t] = 0.0f;
  }
}

// scale 8 k-contiguous bf16 (global k = kg..kg+7) by softmax row(s)
__device__ inline uint4 scale_b8(uint4 raw, int kg, const float* smrow) {
  int r0 = kg / I_;
  int bnd = (r0 + 1) * I_ - kg;                // elements j<bnd use r0
  float s0 = smrow[r0];
  float s1 = smrow[(r0 + 1 < R_) ? r0 + 1 : R_ - 1];
  union { uint4 q; u16 h[8]; } u; u.q = raw;
  #pragma unroll
  for (int j = 0; j < 8; ++j)
    u.h[j] = f2bf(bf2f(u.h[j]) * ((j < bnd) ? s0 : s1));
  return u.q;
}

// ---- GEMM1 + fused split-K reduce + squash.
// grid (4 m-tiles, 12 n-tiles, 10 z). 64x128 tile, BK=32, 4 waves of 64x32.
// Last z-block per (x,y) tile reduces P over z and squashes -> vT / out.
__global__ __launch_bounds__(256) void gemm1_redsq(
    const u16* __restrict__ A, const u16* __restrict__ Bt,
    const float* __restrict__ bij, u16* __restrict__ P,
    int* __restrict__ cnt, float* __restrict__ out, u16* __restrict__ vT,
    int uniformSm, int last) {
  __shared__ u16 As[64 * 32];    // 4 KB (reused as nsq staging in reducer)
  __shared__ u16 Bs[128 * 32];   // 8 KB (reused as factor staging)
  __shared__ float sm[8][192];
  __shared__ int isLast;
  int tid = threadIdx.x;

  // --- per-block softmax table (8 capsules of this n-tile)
  if (uniformSm) {
    for (int j = tid; j < 8 * 192; j += 256) (&sm[0][0])[j] = 1.0f / 192.0f;
  } else {
    int cg = tid >> 5, lr = tid & 31;
    int c = (blockIdx.y << 3) + cg;
    float e[6]; float mx = -1e30f;
    #pragma unroll
    for (int j = 0; j < 6; ++j) {
      e[j] = bij[(lr + (j << 5)) * C_ + c];
      mx = fmaxf(mx, e[j]);
    }
    #pragma unroll
    for (int off = 16; off > 0; off >>= 1) mx = fmaxf(mx, __shfl_xor(mx, off));
    float sum = 0.f;
    #pragma unroll
    for (int j = 0; j < 6; ++j) { e[j] = expf(e[j] - mx); sum += e[j]; }
    #pragma unroll
    for (int off = 16; off > 0; off >>= 1) sum += __shfl_xor(sum, off);
    float inv = 1.0f / sum;
    #pragma unroll
    for (int j = 0; j < 6; ++j) sm[cg][lr + (j << 5)] = e[j] * inv;
  }
  __syncthreads();

  long m0 = (long)blockIdx.x * 64, n0 = (long)blockIdx.y * 128;
  int k0 = blockIdx.z * KCH;
  const u16* Ab = A + m0 * K1 + k0;
  const u16* Bb = Bt + n0 * K1 + k0;
  int srow = tid >> 2;              // 0..63
  int scol = (tid & 3) << 3;        // 0,8,16,24
  int w = tid >> 6, lane = tid & 63;
  int wn = w << 5;                  // wave covers 64m x 32n
  int quad = lane >> 4, lrow = lane & 15;
  int cl0 = srow >> 4;              // c_local of B row srow (0..3)
  floatx4 acc[4][2];
  #pragma unroll
  for (int a = 0; a < 4; ++a)
    #pragma unroll
    for (int b = 0; b < 2; ++b) acc[a][b] = (floatx4){0.f, 0.f, 0.f, 0.f};

  for (int kt = 0; kt < 12; ++kt) {
    int kk = kt << 5;
    uint4 a0 = *(const uint4*)(Ab + (long)srow * K1 + kk + scol);
    uint4 b0 = *(const uint4*)(Bb + (long)srow * K1 + kk + scol);
    uint4 b1 = *(const uint4*)(Bb + (long)(srow + 64) * K1 + kk + scol);
    int kg = k0 + kk + scol;
    uint4 b0s = scale_b8(b0, kg, &sm[cl0][0]);
    uint4 b1s = scale_b8(b1, kg, &sm[cl0 + 4][0]);
    __syncthreads();
    ((uint4*)As)[tid] = a0;
    ((uint4*)Bs)[tid] = b0s;
    ((uint4*)Bs)[tid + 256] = b1s;
    __syncthreads();
    short8 af[4], bfr[2];
    #pragma unroll
    for (int ms = 0; ms < 4; ++ms)
      af[ms] = *(const short8*)&As[(ms * 16 + lrow) * 32 + (quad << 3)];
    #pragma unroll
    for (int ns = 0; ns < 2; ++ns)
      bfr[ns] = *(const short8*)&Bs[(wn + ns * 16 + lrow) * 32 + (quad << 3)];
    #pragma unroll
    for (int ms = 0; ms < 4; ++ms)
      #pragma unroll
      for (int ns = 0; ns < 2; ++ns)
        acc[ms][ns] = __builtin_amdgcn_mfma_f32_16x16x32_bf16(
            af[ms], bfr[ns], acc[ms][ns], 0, 0, 0);
  }
  // transposed bf16 partial store: P[z][n*256 + b]
  size_t zb = (size_t)blockIdx.z * (size_t)STILE;
  #pragma unroll
  for (int ms = 0; ms < 4; ++ms)
    #pragma unroll
    for (int ns = 0; ns < 2; ++ns) {
      int b = (int)m0 + ms * 16 + (quad << 2);
      int n = (int)n0 + wn + ns * 16 + lrow;
      uint2 pk;
      pk.x = pack2(acc[ms][ns][0], acc[ms][ns][1]);
      pk.y = pack2(acc[ms][ns][2], acc[ms][ns][3]);
      *(uint2*)&P[zb + (size_t)n * B_ + b] = pk;
    }

  // --- last-block-per-tile reduction (deadlock-free; no co-residency needed)
  __syncthreads();                       // all stores issued & drained
  if (tid == 0) {
    __threadfence();                     // release: P stores visible device-wide
    int old = atomicAdd(&cnt[blockIdx.y * 4 + blockIdx.x], 1);
    isLast = (old == ZSPLIT - 1);
  }
  __syncthreads();
  if (!isLast) return;
  __threadfence();                       // acquire

  float* nsq_l = (float*)As;             // [16][64]
  float* fac = (float*)Bs;               // [64]
  int o = tid >> 4;                      // 0..15
  int bq = (tid & 15) << 2;              // 0..60 step 4 (local b)
  int b0 = (int)m0;
  for (int cl = 0; cl < 8; ++cl) {
    int n = (int)n0 + cl * 16 + o;       // global n for this capsule/o
    float f[4];
    f[0] = 0.f; f[1] = 0.f; f[2] = 0.f; f[3] = 0.f;
    #pragma unroll
    for (int z = 0; z < ZSPLIT; ++z) {
      uint2 u = *(const uint2*)&P[(size_t)z * STILE + (size_t)n * B_ + b0 + bq];
      f[0] += bf2f((u16)(u.x & 0xffff));
      f[1] += bf2f((u16)(u.x >> 16));
      f[2] += bf2f((u16)(u.y & 0xffff));
      f[3] += bf2f((u16)(u.y >> 16));
    }
    float4 q = (float4){f[0] * f[0], f[1] * f[1], f[2] * f[2], f[3] * f[3]};
    *(float4*)&nsq_l[o * 64 + bq] = q;
    __syncthreads();
    if (tid < 64) {
      float s = 0.f;
      #pragma unroll
      for (int oo = 0; oo < 16; ++oo) s += nsq_l[oo * 64 + tid];
      fac[tid] = s / ((1.0f + s) * sqrtf(s));
    }
    __syncthreads();
    float4 fc = *(const float4*)&fac[bq];
    f[0] *= fc.x; f[1] *= fc.y; f[2] *= fc.z; f[3] *= fc.w;
    if (last) {
      out[(size_t)(b0 + bq + 0) * N_ + n] = f[0];
      out[(size_t)(b0 + bq + 1) * N_ + n] = f[1];
      out[(size_t)(b0 + bq + 2) * N_ + n] = f[2];
      out[(size_t)(b0 + bq + 3) * N_ + n] = f[3];
    } else {
      uint2 pk;
      pk.x = pack2(f[0], f[1]);
      pk.y = pack2(f[2], f[3]);
      *(uint2*)&vT[(size_t)n * B_ + b0 + bq] = pk;
    }
    __syncthreads();                     // nsq_l/fac reuse next capsule
  }
}

// ---- GEMM2 + agreement fused, K split 2x128 (agreement linear in Z).
__global__ __launch_bounds__(256) void gemm2_agree(
    const u16* __restrict__ A, const u16* __restrict__ Bt,
    const u16* __restrict__ WtT, float* __restrict__ bij) {
  const int K = 256;
  __shared__ u16 As[128 * 32];
  __shared__ u16 Bs[128 * 32];
  int tid = threadIdx.x;
  long m0 = (long)blockIdx.x * 128, n0 = (long)blockIdx.y * 128;
  int k0 = blockIdx.z << 7;
  const u16* Ab = A + m0 * K + k0;
  const u16* Bb = Bt + n0 * K + k0;
  int srow = tid >> 2;
  int scol = (tid & 3) << 3;
  int w = tid >> 6, lane = tid & 63;
  int wm = (w >> 1) << 6, wn = (w & 1) << 6;
  int quad = lane >> 4, lrow = lane & 15;
  floatx4 acc[4][4];
  #pragma unroll
  for (int a = 0; a < 4; ++a)
    #pragma unroll
    for (int b = 0; b < 4; ++b) acc[a][b] = (floatx4){0.f, 0.f, 0.f, 0.f};

  for (int kt = 0; kt < 4; ++kt) {
    int kk = kt << 5;
    uint4 a0 = *(const uint4*)(Ab + (long)srow * K + kk + scol);
    uint4 a1 = *(const uint4*)(Ab + (long)(srow + 64) * K + kk + scol);
    uint4 b0 = *(const uint4*)(Bb + (long)srow * K + kk + scol);
    uint4 b1 = *(const uint4*)(Bb + (long)(srow + 64) * K + kk + scol);
    __syncthreads();
    ((uint4*)As)[tid] = a0;
    ((uint4*)As)[tid + 256] = a1;
    ((uint4*)Bs)[tid] = b0;
    ((uint4*)Bs)[tid + 256] = b1;
    __syncthreads();
    short8 af[4], bfr[4];
    #pragma unroll
    for (int ms = 0; ms < 4; ++ms)
      af[ms] = *(const short8*)&As[(wm + ms * 16 + lrow) * 32 + (quad << 3)];
    #pragma unroll
    for (int ns = 0; ns < 4; ++ns)
      bfr[ns] = *(const short8*)&Bs[(wn + ns * 16 + lrow) * 32 + (quad << 3)];
    #pragma unroll
    for (int ms = 0; ms < 4; ++ms)
      #pragma unroll
      for (int ns = 0; ns < 4; ++ns)
        acc[ms][ns] = __builtin_amdgcn_mfma_f32_16x16x32_bf16(
            af[ms], bfr[ns], acc[ms][ns], 0, 0, 0);
  }
  // epilogue: per fragment, cols = one capsule c; 16 rows span <=2 routes r.
  #pragma unroll
  for (int ms = 0; ms < 4; ++ms) {
    int rowbase = (int)m0 + wm + ms * 16;          // wave-uniform
    int r_lo = rowbase / I_;
    int r_hi = (rowbase + 15) / I_;
    int bnd = (r_lo + 1) * I_;
    int rowl = rowbase + (quad << 2);
    #pragma unroll
    for (int ns = 0; ns < 4; ++ns) {
      int col = (int)n0 + wn + ns * 16 + lrow;
      uint2 wv = *(const uint2*)&WtT[(size_t)col * K1 + rowl];
      u16 h[4];
      h[0] = (u16)(wv.x & 0xffff); h[1] = (u16)(wv.x >> 16);
      h[2] = (u16)(wv.y & 0xffff); h[3] = (u16)(wv.y >> 16);
      float p0 = 0.f, p1 = 0.f;
      #pragma unroll
      for (int e = 0; e < 4; ++e) {
        float pr = acc[ms][ns][e] * bf2f(h[e]);
        if (rowl + e < bnd) p0 += pr; else p1 += pr;
      }
      #pragma unroll
      for (int off = 32; off > 0; off >>= 1) {
        p0 += __shfl_xor(p0, off);
        p1 += __shfl_xor(p1, off);
      }
      if (lane == 0) {
        int c = col >> 4;
        atomicAdd(&bij[r_lo * C_ + c], p0 * (1.0f / 256.0f));
        atomicAdd(&bij[r_hi * C_ + c], p1 * (1.0f / 256.0f));
      }
    }
  }
}

extern "C" void kernel_launch(void* const* d_in, const int* in_sizes, int n_in,
                              void* d_out, int out_size, void* d_ws, size_t ws_size,
                              hipStream_t stream) {
  const float* X = (const float*)d_in[0];   // fp32 [256,192,20]
  const float* W = (const float*)d_in[1];   // fp32 [192,96,16,20]
  float* out = (float*)d_out;               // fp32 [256,96,16]
  char* ws = (char*)d_ws;
  u16*  WtT = (u16*)(ws);                   // 11,796,480 B
  u16*  Xk  = (u16*)(ws + 11796480);        //  1,966,080 B
  u16*  xT  = (u16*)(ws + 13762560);        //  1,966,080 B
  u16*  vT  = (u16*)(ws + 15728640);        //    786,432 B
  u16*  Pb  = (u16*)(ws + 16515072);        // 3 iters x 10 z x 786,432 B
  float* bij = (float*)(ws + 40108032);     //     73,728 B
  int*  cnt = (int*)(ws + 40181760);        //        576 B (3 x 48)

  // zeroRegion = bij .. cnt (18432 + 144 dwords), zeroed in prep
  k_prep<<<23353, 256, 0, stream>>>(W, X, WtT, Xk, xT, bij);

  for (int it = 0; it < 3; ++it) {
    gemm1_redsq<<<dim3(4, 12, ZSPLIT), 256, 0, stream>>>(
        Xk, WtT, bij, Pb + (size_t)it * PITER, cnt + it * 48, out, vT,
        it == 0, it == 2);
    if (it < 2)
      gemm2_agree<<<dim3(30, 12, 2), 256, 0, stream>>>(xT, vT, WtT, bij);
  }
}

// Round 7
// 229.889 us; speedup vs baseline: 1.1071x; 1.1071x over previous
//
#include <hip/hip_runtime.h>

// DigitCaps dynamic routing, B=256 R=192 C=96 O=16 I=20. fp32 in/out.
// u_hat never materialized. 11 small dispatches; ALL GEMMs are barrier-free
// (no LDS): MFMA fragments gathered directly from L2-resident operands.
//   prep: W->WtT bf16 k-major; X->Xk + xT; zero bij
//   it0:  gemm1(WtT) -> P^T[z][n][b] bf16 ; redsq(preScale=1/192)
//   it>0: k_scale (softmax(bij)*WtT -> WsT); gemm1(WsT); redsq(1.0)
//   between iters: gemm2_agree (Z-tile in regs, agreement in epilogue,
//   atomicAdd bij), K=256 split 4 ways. NO device fences anywhere.

#define R_ 192
#define C_ 96
#define O_ 16
#define I_ 20
#define B_ 256
#define K1 3840   // R*I
#define N_ 1536   // C*O
#define ZSPLIT 20
#define STILE 393216  // N_*B_ elements per z-slice

typedef unsigned short u16;
typedef __attribute__((ext_vector_type(8))) short short8;
typedef __attribute__((ext_vector_type(4))) float floatx4;

__device__ inline float bf2f(u16 h) {
  union { unsigned int u; float f; } x; x.u = ((unsigned int)h) << 16; return x.f;
}
__device__ inline u16 f2bf(float f) {
  union { float f; unsigned int u; } x; x.f = f;
  unsigned int r = x.u + 0x7FFFu + ((x.u >> 16) & 1u);
  return (u16)(r >> 16);
}
__device__ inline unsigned int pack2(float a, float b) {
  return (unsigned int)f2bf(a) | ((unsigned int)f2bf(b) << 16);
}

// ---- fused prep: WtT gather (23040 blocks); X cast+transpose (240); bij=0 (72)
__global__ void k_prep(const float* __restrict__ W, const float* __restrict__ X,
                       u16* __restrict__ WtT, u16* __restrict__ Xk,
                       u16* __restrict__ xT, float* __restrict__ bij) {
  int bid = blockIdx.x;
  if (bid < 23040) {
    int t = bid * 256 + threadIdx.x;           // over N_*K1 = 5,898,240
    int n = t / K1, k = t - n * K1;
    int c = n >> 4, o = n & 15;
    int r = k / I_, i = k - r * I_;
    WtT[t] = f2bf(W[(((r * C_ + c) * O_ + o) * I_) + i]);
  } else if (bid < 23280) {
    __shared__ u16 tile[64][72];
    int idx = bid - 23040;
    int kb = (idx % 60) << 6, bb = (idx / 60) << 6;
    int brow = threadIdx.x >> 4;          // 0..15
    int kq = (threadIdx.x & 15) << 2;     // 0..60 step 4
    #pragma unroll
    for (int p = 0; p < 4; ++p) {
      int bl = p * 16 + brow;
      float4 v = *(const float4*)(X + (size_t)(bb + bl) * K1 + kb + kq);
      ushort4 h;
      h.x = f2bf(v.x); h.y = f2bf(v.y); h.z = f2bf(v.z); h.w = f2bf(v.w);
      *(ushort4*)(Xk + (size_t)(bb + bl) * K1 + kb + kq) = h;
      tile[kq + 0][bl] = h.x;
      tile[kq + 1][bl] = h.y;
      tile[kq + 2][bl] = h.z;
      tile[kq + 3][bl] = h.w;
    }
    __syncthreads();
    int kr = threadIdx.x >> 3;            // 0..31
    int bq = (threadIdx.x & 7) << 3;      // 0..56 step 8
    #pragma unroll
    for (int q = 0; q < 2; ++q) {
      int kl = q * 32 + kr;
      *(uint4*)(xT + (size_t)(kb + kl) * B_ + bb + bq) = *(const uint4*)&tile[kl][bq];
    }
  } else {
    int t = (bid - 23280) * 256 + threadIdx.x;  // bij: 18,432 floats
    bij[t] = 0.0f;
  }
}

// ---- softmax + scale: one block per n-row; WsT[n,:] = WtT[n,:]*softmax(bij)[r,c]
__global__ void k_scale(const u16* __restrict__ WtT, const float* __restrict__ bij,
                        u16* __restrict__ WsT) {
  __shared__ float sm[192];
  __shared__ float wred[4];
  int n = blockIdx.x, t = threadIdx.x;
  int c = n >> 4;
  float v = (t < R_) ? bij[t * C_ + c] : -1e30f;
  float m = v;
  #pragma unroll
  for (int off = 32; off > 0; off >>= 1) m = fmaxf(m, __shfl_xor(m, off));
  if ((t & 63) == 0) wred[t >> 6] = m;
  __syncthreads();
  m = fmaxf(fmaxf(wred[0], wred[1]), fmaxf(wred[2], wred[3]));
  float e = (t < R_) ? expf(v - m) : 0.0f;
  float ssum = e;
  #pragma unroll
  for (int off = 32; off > 0; off >>= 1) ssum += __shfl_xor(ssum, off);
  __syncthreads();
  if ((t & 63) == 0) wred[t >> 6] = ssum;
  __syncthreads();
  ssum = wred[0] + wred[1] + wred[2] + wred[3];
  if (t < R_) sm[t] = e / ssum;
  __syncthreads();
  const uint4* src = (const uint4*)WtT + (size_t)n * 480;
  uint4* dst = (uint4*)WsT + (size_t)n * 480;
  for (int idx = t; idx < 480; idx += 256) {
    union { uint4 q; u16 h[8]; } u; u.q = src[idx];
    int k0 = idx << 3;
    #pragma unroll
    for (int eidx = 0; eidx < 8; ++eidx) {
      int r = (k0 + eidx) / I_;
      u.h[eidx] = f2bf(bf2f(u.h[eidx]) * sm[r]);
    }
    dst[idx] = u.q;
  }
}

// ---- GEMM1, barrier-free: P^T[z][n][b] bf16 = (A[256,3840] x B[1536,3840]^T)
// k-chunk z. 128x128 tile, 4 waves of 64x64; fragments gathered directly
// from global (16 B/lane, contiguous in k). No LDS, no __syncthreads.
__global__ __launch_bounds__(256) void gemm1(
    const u16* __restrict__ A, const u16* __restrict__ Bt,
    u16* __restrict__ P, int kIters) {
  int tid = threadIdx.x;
  int w = tid >> 6, lane = tid & 63;
  int wm = (w >> 1) << 6, wn = (w & 1) << 6;
  int quad = lane >> 4, lrow = lane & 15;
  int m0 = blockIdx.x << 7, n0 = blockIdx.y << 7;
  int k0 = blockIdx.z * (kIters << 5);
  const u16* Ab = A + (size_t)(m0 + wm + lrow) * K1 + k0 + (quad << 3);
  const u16* Bb = Bt + (size_t)(n0 + wn + lrow) * K1 + k0 + (quad << 3);
  floatx4 acc[4][4];
  #pragma unroll
  for (int a = 0; a < 4; ++a)
    #pragma unroll
    for (int b = 0; b < 4; ++b) acc[a][b] = (floatx4){0.f, 0.f, 0.f, 0.f};

  for (int kt = 0; kt < kIters; ++kt) {
    const u16* Ak = Ab + (kt << 5);
    const u16* Bk = Bb + (kt << 5);
    short8 af[4], bfr[4];
    #pragma unroll
    for (int ms = 0; ms < 4; ++ms)
      af[ms] = *(const short8*)(Ak + (size_t)(ms * 16) * K1);
    #pragma unroll
    for (int ns = 0; ns < 4; ++ns)
      bfr[ns] = *(const short8*)(Bk + (size_t)(ns * 16) * K1);
    #pragma unroll
    for (int ms = 0; ms < 4; ++ms)
      #pragma unroll
      for (int ns = 0; ns < 4; ++ns)
        acc[ms][ns] = __builtin_amdgcn_mfma_f32_16x16x32_bf16(
            af[ms], bfr[ns], acc[ms][ns], 0, 0, 0);
  }
  // transposed bf16 store: P[z][n*256 + b]; lane holds 4 consecutive b
  size_t zb = (size_t)blockIdx.z * (size_t)STILE;
  #pragma unroll
  for (int ms = 0; ms < 4; ++ms)
    #pragma unroll
    for (int ns = 0; ns < 4; ++ns) {
      int b = m0 + wm + ms * 16 + (quad << 2);
      int n = n0 + wn + ns * 16 + lrow;
      uint2 pk;
      pk.x = pack2(acc[ms][ns][0], acc[ms][ns][1]);
      pk.y = pack2(acc[ms][ns][2], acc[ms][ns][3]);
      *(uint2*)&P[zb + (size_t)n * B_ + b] = pk;
    }
}

// ---- fused split-K reduce + squash, reading P^T[z][n][b] bf16.
// grid (96 c, 2 b-halves), block 256 = 4 o-groups x 64 lanes; 2 b per lane.
__global__ void k_redsq(const u16* __restrict__ P, float* __restrict__ out,
                        u16* __restrict__ vT, float preScale, int last) {
  __shared__ float nsq_l[4][128];
  int c = blockIdx.x, bh = blockIdx.y;
  int lane = threadIdx.x & 63, og = threadIdx.x >> 6;
  int bi = (lane << 1);                  // local b index (0..126 step 2)
  int b = (bh << 7) + bi;
  float acc[4][2];
  #pragma unroll
  for (int oo = 0; oo < 4; ++oo) { acc[oo][0] = 0.f; acc[oo][1] = 0.f; }
  for (int z = 0; z < ZSPLIT; ++z) {
    size_t base = (size_t)z * STILE + (size_t)((c << 4) + (og << 2)) * B_ + b;
    #pragma unroll
    for (int oo = 0; oo < 4; ++oo) {
      unsigned int u = *(const unsigned int*)&P[base + (size_t)oo * B_];
      acc[oo][0] += bf2f((u16)(u & 0xffff));
      acc[oo][1] += bf2f((u16)(u >> 16));
    }
  }
  #pragma unroll
  for (int oo = 0; oo < 4; ++oo) { acc[oo][0] *= preScale; acc[oo][1] *= preScale; }
  float q0 = 0.f, q1 = 0.f;
  #pragma unroll
  for (int oo = 0; oo < 4; ++oo) {
    q0 += acc[oo][0] * acc[oo][0];
    q1 += acc[oo][1] * acc[oo][1];
  }
  nsq_l[og][bi] = q0;
  nsq_l[og][bi + 1] = q1;
  __syncthreads();
  float n0 = nsq_l[0][bi] + nsq_l[1][bi] + nsq_l[2][bi] + nsq_l[3][bi];
  float n1 = nsq_l[0][bi + 1] + nsq_l[1][bi + 1] + nsq_l[2][bi + 1] + nsq_l[3][bi + 1];
  float f0 = n0 / ((1.0f + n0) * sqrtf(n0));
  float f1 = n1 / ((1.0f + n1) * sqrtf(n1));
  #pragma unroll
  for (int oo = 0; oo < 4; ++oo) { acc[oo][0] *= f0; acc[oo][1] *= f1; }
  if (last) {
    float4 v0 = (float4){acc[0][0], acc[1][0], acc[2][0], acc[3][0]};
    float4 v1 = (float4){acc[0][1], acc[1][1], acc[2][1], acc[3][1]};
    *(float4*)(out + (size_t)b * N_ + (c << 4) + (og << 2)) = v0;
    *(float4*)(out + (size_t)(b + 1) * N_ + (c << 4) + (og << 2)) = v1;
  } else {
    #pragma unroll
    for (int oo = 0; oo < 4; ++oo)
      *(unsigned int*)&vT[(size_t)((c << 4) + (og << 2) + oo) * B_ + b] =
          pack2(acc[oo][0], acc[oo][1]);
  }
}

// ---- GEMM2 + agreement, barrier-free. M=3840,N=1536,K=256 split 4x64.
// Z-tile in regs; epilogue contracts vs WtT, atomicAdd into bij.
__global__ __launch_bounds__(256) void gemm2_agree(
    const u16* __restrict__ A, const u16* __restrict__ Bt,
    const u16* __restrict__ WtT, float* __restrict__ bij) {
  int tid = threadIdx.x;
  int w = tid >> 6, lane = tid & 63;
  int wm = (w >> 1) << 6, wn = (w & 1) << 6;
  int quad = lane >> 4, lrow = lane & 15;
  int m0 = blockIdx.x << 7, n0 = blockIdx.y << 7;
  int k0 = blockIdx.z << 6;
  const u16* Ab = A + (size_t)(m0 + wm + lrow) * B_ + k0 + (quad << 3);
  const u16* Bb = Bt + (size_t)(n0 + wn + lrow) * B_ + k0 + (quad << 3);
  floatx4 acc[4][4];
  #pragma unroll
  for (int a = 0; a < 4; ++a)
    #pragma unroll
    for (int b = 0; b < 4; ++b) acc[a][b] = (floatx4){0.f, 0.f, 0.f, 0.f};

  #pragma unroll
  for (int kt = 0; kt < 2; ++kt) {
    const u16* Ak = Ab + (kt << 5);
    const u16* Bk = Bb + (kt << 5);
    short8 af[4], bfr[4];
    #pragma unroll
    for (int ms = 0; ms < 4; ++ms)
      af[ms] = *(const short8*)(Ak + (size_t)(ms * 16) * B_);
    #pragma unroll
    for (int ns = 0; ns < 4; ++ns)
      bfr[ns] = *(const short8*)(Bk + (size_t)(ns * 16) * B_);
    #pragma unroll
    for (int ms = 0; ms < 4; ++ms)
      #pragma unroll
      for (int ns = 0; ns < 4; ++ns)
        acc[ms][ns] = __builtin_amdgcn_mfma_f32_16x16x32_bf16(
            af[ms], bfr[ns], acc[ms][ns], 0, 0, 0);
  }
  // epilogue: per fragment, cols = one capsule c; 16 rows span <=2 routes r.
  #pragma unroll
  for (int ms = 0; ms < 4; ++ms) {
    int rowbase = m0 + wm + ms * 16;               // wave-uniform
    int r_lo = rowbase / I_;
    int r_hi = (rowbase + 15) / I_;
    int bnd = (r_lo + 1) * I_;
    int rowl = rowbase + (quad << 2);
    #pragma unroll
    for (int ns = 0; ns < 4; ++ns) {
      int col = n0 + wn + ns * 16 + lrow;
      uint2 wv = *(const uint2*)&WtT[(size_t)col * K1 + rowl];
      u16 h[4];
      h[0] = (u16)(wv.x & 0xffff); h[1] = (u16)(wv.x >> 16);
      h[2] = (u16)(wv.y & 0xffff); h[3] = (u16)(wv.y >> 16);
      float p0 = 0.f, p1 = 0.f;
      #pragma unroll
      for (int e = 0; e < 4; ++e) {
        float pr = acc[ms][ns][e] * bf2f(h[e]);
        if (rowl + e < bnd) p0 += pr; else p1 += pr;
      }
      #pragma unroll
      for (int off = 32; off > 0; off >>= 1) {
        p0 += __shfl_xor(p0, off);
        p1 += __shfl_xor(p1, off);
      }
      if (lane == 0) {
        int c = col >> 4;
        atomicAdd(&bij[r_lo * C_ + c], p0 * (1.0f / 256.0f));
        atomicAdd(&bij[r_hi * C_ + c], p1 * (1.0f / 256.0f));
      }
    }
  }
}

extern "C" void kernel_launch(void* const* d_in, const int* in_sizes, int n_in,
                              void* d_out, int out_size, void* d_ws, size_t ws_size,
                              hipStream_t stream) {
  const float* X = (const float*)d_in[0];   // fp32 [256,192,20]
  const float* W = (const float*)d_in[1];   // fp32 [192,96,16,20]
  float* out = (float*)d_out;               // fp32 [256,96,16]
  char* ws = (char*)d_ws;
  u16*  WtT = (u16*)(ws);                   // 11,796,480 B
  u16*  WsT = (u16*)(ws + 11796480);        // 11,796,480 B
  u16*  Xk  = (u16*)(ws + 23592960);        //  1,966,080 B
  u16*  xT  = (u16*)(ws + 25559040);        //  1,966,080 B
  u16*  vT  = (u16*)(ws + 27525120);        //    786,432 B
  u16*  Pb  = (u16*)(ws + 28311552);        // 20 z x 786,432 B = 15,728,640 B
  float* bij = (float*)(ws + 44040192);     //     73,728 B

  k_prep<<<23352, 256, 0, stream>>>(W, X, WtT, Xk, xT, bij);

  for (int it = 0; it < 3; ++it) {
    const u16* Bmat = WtT;
    if (it > 0) {
      k_scale<<<1536, 256, 0, stream>>>(WtT, bij, WsT);
      Bmat = WsT;
    }
    // s partials: M=256,N=1536,K=3840 split 20 ways (chunk 192 = 6 k-iters).
    // it==0: B unscaled; the uniform softmax 1/192 is applied in k_redsq.
    gemm1<<<dim3(2, 12, ZSPLIT), 256, 0, stream>>>(Xk, Bmat, Pb, 6);
    k_redsq<<<dim3(96, 2), 256, 0, stream>>>(
        Pb, out, vT, it == 0 ? (1.0f / 192.0f) : 1.0f, it == 2);
    if (it < 2)
      gemm2_agree<<<dim3(30, 12, 4), 256, 0, stream>>>(xT, vT, WtT, bij);
  }
}

// Round 8
// 176.049 us; speedup vs baseline: 1.4457x; 1.3058x over previous
//
#include <hip/hip_runtime.h>

// DigitCaps dynamic routing, B=256 R=192 C=96 O=16 I=20. fp32 in/out.
// u_hat never materialized. 9 dispatches:
//   prep: W->WtT bf16 k-major; X->Xk + xT; bij=0
//   gemm1 (x3): softmax(bij) per block folded into B LDS-staging; K split 20;
//     software-pipelined K-loop (prefetch regs + double LDS, 1 barrier/iter);
//     partials stored transposed bf16 P^T[z][n][b]
//   redsq (x3): coalesced split-K reduce + squash -> vT (bf16) / out (fp32)
//   gemm2_agree (x2): LDS-staged, pipelined; Z-tile in regs; agreement
//     contracted in epilogue vs WtT, atomicAdd into bij. K=256 split 2.

#define R_ 192
#define C_ 96
#define O_ 16
#define I_ 20
#define B_ 256
#define K1 3840   // R*I
#define N_ 1536   // C*O
#define ZSPLIT 20
#define STILE 393216  // N_*B_ elements per z-slice

typedef unsigned short u16;
typedef __attribute__((ext_vector_type(8))) short short8;
typedef __attribute__((ext_vector_type(4))) float floatx4;

__device__ inline float bf2f(u16 h) {
  union { unsigned int u; float f; } x; x.u = ((unsigned int)h) << 16; return x.f;
}
__device__ inline u16 f2bf(float f) {
  union { float f; unsigned int u; } x; x.f = f;
  unsigned int r = x.u + 0x7FFFu + ((x.u >> 16) & 1u);
  return (u16)(r >> 16);
}
__device__ inline unsigned int pack2(float a, float b) {
  return (unsigned int)f2bf(a) | ((unsigned int)f2bf(b) << 16);
}

// ---- fused prep: WtT gather (23040 blocks); X cast+transpose (240); bij=0 (72)
__global__ void k_prep(const float* __restrict__ W, const float* __restrict__ X,
                       u16* __restrict__ WtT, u16* __restrict__ Xk,
                       u16* __restrict__ xT, float* __restrict__ bij) {
  int bid = blockIdx.x;
  if (bid < 23040) {
    int t = bid * 256 + threadIdx.x;           // over N_*K1 = 5,898,240
    int n = t / K1, k = t - n * K1;
    int c = n >> 4, o = n & 15;
    int r = k / I_, i = k - r * I_;
    WtT[t] = f2bf(W[(((r * C_ + c) * O_ + o) * I_) + i]);
  } else if (bid < 23280) {
    __shared__ u16 tile[64][72];
    int idx = bid - 23040;
    int kb = (idx % 60) << 6, bb = (idx / 60) << 6;
    int brow = threadIdx.x >> 4;          // 0..15
    int kq = (threadIdx.x & 15) << 2;     // 0..60 step 4
    #pragma unroll
    for (int p = 0; p < 4; ++p) {
      int bl = p * 16 + brow;
      float4 v = *(const float4*)(X + (size_t)(bb + bl) * K1 + kb + kq);
      ushort4 h;
      h.x = f2bf(v.x); h.y = f2bf(v.y); h.z = f2bf(v.z); h.w = f2bf(v.w);
      *(ushort4*)(Xk + (size_t)(bb + bl) * K1 + kb + kq) = h;
      tile[kq + 0][bl] = h.x;
      tile[kq + 1][bl] = h.y;
      tile[kq + 2][bl] = h.z;
      tile[kq + 3][bl] = h.w;
    }
    __syncthreads();
    int kr = threadIdx.x >> 3;            // 0..31
    int bq = (threadIdx.x & 7) << 3;      // 0..56 step 8
    #pragma unroll
    for (int q = 0; q < 2; ++q) {
      int kl = q * 32 + kr;
      *(uint4*)(xT + (size_t)(kb + kl) * B_ + bb + bq) = *(const uint4*)&tile[kl][bq];
    }
  } else {
    int t = (bid - 23280) * 256 + threadIdx.x;  // bij: 18,432 floats
    bij[t] = 0.0f;
  }
}

// scale 8 k-contiguous bf16 (global k = kg..kg+7) by softmax row(s)
__device__ inline uint4 scale_b8(uint4 raw, int kg, const float* smrow) {
  int r0 = kg / I_;
  int bnd = (r0 + 1) * I_ - kg;                // elements j<bnd use r0
  float s0 = smrow[r0];
  float s1 = smrow[(r0 + 1 < R_) ? r0 + 1 : R_ - 1];
  union { uint4 q; u16 h[8]; } u; u.q = raw;
  #pragma unroll
  for (int j = 0; j < 8; ++j)
    u.h[j] = f2bf(bf2f(u.h[j]) * ((j < bnd) ? s0 : s1));
  return u.q;
}

// ---- GEMM1: P^T[z][n][b] bf16 = (Xk[256,3840] x (c*WtT)[1536,3840]^T),
// k-chunk z. 128x128 tile, BK=32, 4 waves of 64x64. Software-pipelined:
// raw prefetch issued AFTER the barrier (escapes the pre-barrier vmcnt(0)
// drain), consumed at next iter's LDS-write; double LDS, 1 barrier/iter.
__global__ __launch_bounds__(256) void gemm1(
    const u16* __restrict__ A, const u16* __restrict__ Bt,
    const float* __restrict__ bij, u16* __restrict__ P,
    int kChunk, int kIters) {
  __shared__ u16 As[2][128 * 32];
  __shared__ u16 Bs[2][128 * 32];
  __shared__ float sm[8][192];
  int tid = threadIdx.x;
  // --- per-block softmax table (8 capsules of this n-tile)
  {
    int cg = tid >> 5, lr = tid & 31;
    int c = (blockIdx.y << 3) + cg;
    float e[6]; float mx = -1e30f;
    #pragma unroll
    for (int j = 0; j < 6; ++j) {
      e[j] = bij[(lr + (j << 5)) * C_ + c];
      mx = fmaxf(mx, e[j]);
    }
    #pragma unroll
    for (int off = 16; off > 0; off >>= 1) mx = fmaxf(mx, __shfl_xor(mx, off));
    float sum = 0.f;
    #pragma unroll
    for (int j = 0; j < 6; ++j) { e[j] = expf(e[j] - mx); sum += e[j]; }
    #pragma unroll
    for (int off = 16; off > 0; off >>= 1) sum += __shfl_xor(sum, off);
    float inv = 1.0f / sum;
    #pragma unroll
    for (int j = 0; j < 6; ++j) sm[cg][lr + (j << 5)] = e[j] * inv;
  }

  long m0 = (long)blockIdx.x * 128, n0 = (long)blockIdx.y * 128;
  int k0 = blockIdx.z * kChunk;
  const u16* Ab = A + m0 * K1 + k0;
  const u16* Bb = Bt + n0 * K1 + k0;
  int srow = tid >> 2;              // 0..63 (+64 for second row)
  int scol = (tid & 3) << 3;        // 0,8,16,24
  int w = tid >> 6, lane = tid & 63;
  int wm = (w >> 1) << 6, wn = (w & 1) << 6;
  int quad = lane >> 4, lrow = lane & 15;
  int cl0 = srow >> 4;              // c_local of B row srow (0..3)
  floatx4 acc[4][4];
  #pragma unroll
  for (int a = 0; a < 4; ++a)
    #pragma unroll
    for (int b = 0; b < 4; ++b) acc[a][b] = (floatx4){0.f, 0.f, 0.f, 0.f};

  // initial raw load (kt = 0)
  uint4 a0 = *(const uint4*)(Ab + (long)srow * K1 + scol);
  uint4 a1 = *(const uint4*)(Ab + (long)(srow + 64) * K1 + scol);
  uint4 b0 = *(const uint4*)(Bb + (long)srow * K1 + scol);
  uint4 b1 = *(const uint4*)(Bb + (long)(srow + 64) * K1 + scol);
  __syncthreads();                   // sm table ready

  int p = 0;
  for (int kt = 0; kt < kIters; ++kt) {
    int kg = k0 + (kt << 5) + scol;
    ((uint4*)As[p])[tid] = a0;
    ((uint4*)As[p])[tid + 256] = a1;
    ((uint4*)Bs[p])[tid] = scale_b8(b0, kg, &sm[cl0][0]);
    ((uint4*)Bs[p])[tid + 256] = scale_b8(b1, kg, &sm[cl0 + 4][0]);
    __syncthreads();
    if (kt + 1 < kIters) {           // prefetch escapes the barrier drain
      int kk = (kt + 1) << 5;
      a0 = *(const uint4*)(Ab + (long)srow * K1 + kk + scol);
      a1 = *(const uint4*)(Ab + (long)(srow + 64) * K1 + kk + scol);
      b0 = *(const uint4*)(Bb + (long)srow * K1 + kk + scol);
      b1 = *(const uint4*)(Bb + (long)(srow + 64) * K1 + kk + scol);
    }
    short8 af[4], bfr[4];
    #pragma unroll
    for (int ms = 0; ms < 4; ++ms)
      af[ms] = *(const short8*)&As[p][(wm + ms * 16 + lrow) * 32 + (quad << 3)];
    #pragma unroll
    for (int ns = 0; ns < 4; ++ns)
      bfr[ns] = *(const short8*)&Bs[p][(wn + ns * 16 + lrow) * 32 + (quad << 3)];
    #pragma unroll
    for (int ms = 0; ms < 4; ++ms)
      #pragma unroll
      for (int ns = 0; ns < 4; ++ns)
        acc[ms][ns] = __builtin_amdgcn_mfma_f32_16x16x32_bf16(
            af[ms], bfr[ns], acc[ms][ns], 0, 0, 0);
    p ^= 1;
  }
  // transposed bf16 store: P[z][n*256 + b]; lane holds 4 consecutive b
  size_t zb = (size_t)blockIdx.z * (size_t)STILE;
  #pragma unroll
  for (int ms = 0; ms < 4; ++ms)
    #pragma unroll
    for (int ns = 0; ns < 4; ++ns) {
      int b = (int)m0 + wm + ms * 16 + (quad << 2);
      int n = (int)n0 + wn + ns * 16 + lrow;
      uint2 pk;
      pk.x = pack2(acc[ms][ns][0], acc[ms][ns][1]);
      pk.y = pack2(acc[ms][ns][2], acc[ms][ns][3]);
      *(uint2*)&P[zb + (size_t)n * B_ + b] = pk;
    }
}

// ---- fused split-K reduce + squash, reading P^T[z][n][b] bf16.
// grid (96 c, 2 b-halves), block 256 = 4 o-groups x 64 lanes; 2 b per lane.
__global__ void k_redsq(const u16* __restrict__ P, float* __restrict__ out,
                        u16* __restrict__ vT, int last) {
  __shared__ float nsq_l[4][128];
  int c = blockIdx.x, bh = blockIdx.y;
  int lane = threadIdx.x & 63, og = threadIdx.x >> 6;
  int bi = (lane << 1);                  // local b index (0..126 step 2)
  int b = (bh << 7) + bi;
  float acc[4][2];
  #pragma unroll
  for (int oo = 0; oo < 4; ++oo) { acc[oo][0] = 0.f; acc[oo][1] = 0.f; }
  for (int z = 0; z < ZSPLIT; ++z) {
    size_t base = (size_t)z * STILE + (size_t)((c << 4) + (og << 2)) * B_ + b;
    #pragma unroll
    for (int oo = 0; oo < 4; ++oo) {
      unsigned int u = *(const unsigned int*)&P[base + (size_t)oo * B_];
      acc[oo][0] += bf2f((u16)(u & 0xffff));
      acc[oo][1] += bf2f((u16)(u >> 16));
    }
  }
  float q0 = 0.f, q1 = 0.f;
  #pragma unroll
  for (int oo = 0; oo < 4; ++oo) {
    q0 += acc[oo][0] * acc[oo][0];
    q1 += acc[oo][1] * acc[oo][1];
  }
  nsq_l[og][bi] = q0;
  nsq_l[og][bi + 1] = q1;
  __syncthreads();
  float n0 = nsq_l[0][bi] + nsq_l[1][bi] + nsq_l[2][bi] + nsq_l[3][bi];
  float n1 = nsq_l[0][bi + 1] + nsq_l[1][bi + 1] + nsq_l[2][bi + 1] + nsq_l[3][bi + 1];
  float f0 = n0 / ((1.0f + n0) * sqrtf(n0));
  float f1 = n1 / ((1.0f + n1) * sqrtf(n1));
  #pragma unroll
  for (int oo = 0; oo < 4; ++oo) { acc[oo][0] *= f0; acc[oo][1] *= f1; }
  if (last) {
    float4 v0 = (float4){acc[0][0], acc[1][0], acc[2][0], acc[3][0]};
    float4 v1 = (float4){acc[0][1], acc[1][1], acc[2][1], acc[3][1]};
    *(float4*)(out + (size_t)b * N_ + (c << 4) + (og << 2)) = v0;
    *(float4*)(out + (size_t)(b + 1) * N_ + (c << 4) + (og << 2)) = v1;
  } else {
    #pragma unroll
    for (int oo = 0; oo < 4; ++oo)
      *(unsigned int*)&vT[(size_t)((c << 4) + (og << 2) + oo) * B_ + b] =
          pack2(acc[oo][0], acc[oo][1]);
  }
}

// ---- GEMM2 + agreement fused, K=256 split 2x128, LDS-staged + pipelined.
// Z-tile stays in regs; epilogue contracts vs WtT, atomicAdd into bij.
__global__ __launch_bounds__(256) void gemm2_agree(
    const u16* __restrict__ A, const u16* __restrict__ Bt,
    const u16* __restrict__ WtT, float* __restrict__ bij) {
  const int K = 256;
  __shared__ u16 As[2][128 * 32];
  __shared__ u16 Bs[2][128 * 32];
  int tid = threadIdx.x;
  long m0 = (long)blockIdx.x * 128, n0 = (long)blockIdx.y * 128;
  int k0 = blockIdx.z << 7;
  const u16* Ab = A + m0 * K + k0;
  const u16* Bb = Bt + n0 * K + k0;
  int srow = tid >> 2;
  int scol = (tid & 3) << 3;
  int w = tid >> 6, lane = tid & 63;
  int wm = (w >> 1) << 6, wn = (w & 1) << 6;
  int quad = lane >> 4, lrow = lane & 15;
  floatx4 acc[4][4];
  #pragma unroll
  for (int a = 0; a < 4; ++a)
    #pragma unroll
    for (int b = 0; b < 4; ++b) acc[a][b] = (floatx4){0.f, 0.f, 0.f, 0.f};

  uint4 a0 = *(const uint4*)(Ab + (long)srow * K + scol);
  uint4 a1 = *(const uint4*)(Ab + (long)(srow + 64) * K + scol);
  uint4 b0 = *(const uint4*)(Bb + (long)srow * K + scol);
  uint4 b1 = *(const uint4*)(Bb + (long)(srow + 64) * K + scol);

  int p = 0;
  #pragma unroll
  for (int kt = 0; kt < 4; ++kt) {
    ((uint4*)As[p])[tid] = a0;
    ((uint4*)As[p])[tid + 256] = a1;
    ((uint4*)Bs[p])[tid] = b0;
    ((uint4*)Bs[p])[tid + 256] = b1;
    __syncthreads();
    if (kt + 1 < 4) {
      int kk = (kt + 1) << 5;
      a0 = *(const uint4*)(Ab + (long)srow * K + kk + scol);
      a1 = *(const uint4*)(Ab + (long)(srow + 64) * K + kk + scol);
      b0 = *(const uint4*)(Bb + (long)srow * K + kk + scol);
      b1 = *(const uint4*)(Bb + (long)(srow + 64) * K + kk + scol);
    }
    short8 af[4], bfr[4];
    #pragma unroll
    for (int ms = 0; ms < 4; ++ms)
      af[ms] = *(const short8*)&As[p][(wm + ms * 16 + lrow) * 32 + (quad << 3)];
    #pragma unroll
    for (int ns = 0; ns < 4; ++ns)
      bfr[ns] = *(const short8*)&Bs[p][(wn + ns * 16 + lrow) * 32 + (quad << 3)];
    #pragma unroll
    for (int ms = 0; ms < 4; ++ms)
      #pragma unroll
      for (int ns = 0; ns < 4; ++ns)
        acc[ms][ns] = __builtin_amdgcn_mfma_f32_16x16x32_bf16(
            af[ms], bfr[ns], acc[ms][ns], 0, 0, 0);
    p ^= 1;
  }
  // epilogue: per fragment, cols = one capsule c; 16 rows span <=2 routes r.
  #pragma unroll
  for (int ms = 0; ms < 4; ++ms) {
    int rowbase = (int)m0 + wm + ms * 16;          // wave-uniform
    int r_lo = rowbase / I_;
    int r_hi = (rowbase + 15) / I_;
    int bnd = (r_lo + 1) * I_;
    int rowl = rowbase + (quad << 2);
    #pragma unroll
    for (int ns = 0; ns < 4; ++ns) {
      int col = (int)n0 + wn + ns * 16 + lrow;
      uint2 wv = *(const uint2*)&WtT[(size_t)col * K1 + rowl];
      u16 h[4];
      h[0] = (u16)(wv.x & 0xffff); h[1] = (u16)(wv.x >> 16);
      h[2] = (u16)(wv.y & 0xffff); h[3] = (u16)(wv.y >> 16);
      float p0 = 0.f, p1 = 0.f;
      #pragma unroll
      for (int e = 0; e < 4; ++e) {
        float pr = acc[ms][ns][e] * bf2f(h[e]);
        if (rowl + e < bnd) p0 += pr; else p1 += pr;
      }
      #pragma unroll
      for (int off = 32; off > 0; off >>= 1) {
        p0 += __shfl_xor(p0, off);
        p1 += __shfl_xor(p1, off);
      }
      if (lane == 0) {
        int c = col >> 4;
        atomicAdd(&bij[r_lo * C_ + c], p0 * (1.0f / 256.0f));
        atomicAdd(&bij[r_hi * C_ + c], p1 * (1.0f / 256.0f));
      }
    }
  }
}

extern "C" void kernel_launch(void* const* d_in, const int* in_sizes, int n_in,
                              void* d_out, int out_size, void* d_ws, size_t ws_size,
                              hipStream_t stream) {
  const float* X = (const float*)d_in[0];   // fp32 [256,192,20]
  const float* W = (const float*)d_in[1];   // fp32 [192,96,16,20]
  float* out = (float*)d_out;               // fp32 [256,96,16]
  char* ws = (char*)d_ws;
  u16*  WtT = (u16*)(ws);                   // 11,796,480 B
  u16*  Xk  = (u16*)(ws + 11796480);        //  1,966,080 B
  u16*  xT  = (u16*)(ws + 13762560);        //  1,966,080 B
  u16*  vT  = (u16*)(ws + 15728640);        //    786,432 B
  u16*  Pb  = (u16*)(ws + 16515072);        // 20 z x 786,432 B = 15,728,640 B
  float* bij = (float*)(ws + 32243712);     //     73,728 B

  k_prep<<<23352, 256, 0, stream>>>(W, X, WtT, Xk, xT, bij);

  for (int it = 0; it < 3; ++it) {
    // s partials: M=256,N=1536,K=3840 split 20 ways (chunk 192 = 6 k-iters);
    // softmax+scale folded in (iter 0: bij==0 -> uniform 1/192 automatically)
    gemm1<<<dim3(2, 12, ZSPLIT), 256, 0, stream>>>(Xk, WtT, bij, Pb, 192, 6);
    k_redsq<<<dim3(96, 2), 256, 0, stream>>>(Pb, out, vT, it == 2);
    if (it < 2)
      gemm2_agree<<<dim3(30, 12, 2), 256, 0, stream>>>(xT, vT, WtT, bij);
  }
}